// Round 10
// baseline (545.014 us; speedup 1.0000x reference)
//
#include <hip/hip_runtime.h>

typedef float f32x4 __attribute__((ext_vector_type(4)));
typedef short bf16x8 __attribute__((ext_vector_type(8)));
typedef unsigned short u16;
typedef u16 u16x8 __attribute__((ext_vector_type(8)));
typedef unsigned int u32;

#define B 4
#define C 256
#define K 64
#define NN 4096
#define W3C 768
#define CP 264   // muT LDS pitch (shorts)
#define SP 72    // sigmaT LDS pitch (shorts)
#define LGP 68   // logits LDS pitch (floats)

__device__ __forceinline__ u16 bf_hi(float f) {
    unsigned u = __float_as_uint(f);
    u += 0x7FFFu + ((u >> 16) & 1u);
    return (u16)(u >> 16);
}
__device__ __forceinline__ float bf_f(u16 s) { return __uint_as_float(((unsigned)s) << 16); }

// ================= merged prep: single x read -> both layouts; w_cat; mu; cnt =================
// grid 4449 x 256
__global__ void k_prep(const float* __restrict__ x, const float* __restrict__ mu0,
                       const float* __restrict__ w_cat,
                       u16* __restrict__ xch, u16* __restrict__ xcl,
                       u16* __restrict__ xth, u16* __restrict__ xtl,
                       u16* __restrict__ wch, u16* __restrict__ wcl,
                       u16* __restrict__ muth, u16* __restrict__ mutl,
                       u32* __restrict__ cnt) {
    __shared__ float tile[32][33];
    int blk = blockIdx.x, tid = threadIdx.x;
    if (blk < 4096) {
        // 32x32 tile of x: emit transposed (xth/xtl) AND c-major (xch/xcl) bf16 hi/lo
        int b2 = blk >> 10, rem = blk & 1023;
        int c0 = (rem >> 7) << 5, m0 = (rem & 127) << 5;
        int tx = tid & 31, ty = tid >> 5;   // ty in 0..7
        #pragma unroll
        for (int j = 0; j < 4; j++)
            tile[ty + j * 8][tx] = x[((size_t)(b2 * C + c0 + ty + j * 8)) * NN + m0 + tx];
        __syncthreads();
        #pragma unroll
        for (int j = 0; j < 4; j++) {
            // c-major: row c = c0+ty+j*8, col n = m0+tx
            float vc = tile[ty + j * 8][tx];
            u16 hc = bf_hi(vc);
            size_t oc = ((size_t)(b2 * C + c0 + ty + j * 8)) * NN + m0 + tx;
            xch[oc] = hc;
            xcl[oc] = bf_hi(vc - bf_f(hc));
            // n-major: row n = m0+ty+j*8, col c = c0+tx
            float vt = tile[tx][ty + j * 8];
            u16 ht = bf_hi(vt);
            size_t ot = ((size_t)(b2 * NN + m0 + ty + j * 8)) * C + c0 + tx;
            xth[ot] = ht;
            xtl[ot] = bf_hi(vt - bf_f(ht));
        }
    } else if (blk < 4192) {
        int i = (blk - 4096) * 256 + tid;   // 96 blocks x 256 = 24576 = C*W3C/8
        const float4* s4 = (const float4*)(w_cat + (size_t)i * 8);
        float4 a = s4[0], bq = s4[1];
        float v[8] = {a.x, a.y, a.z, a.w, bq.x, bq.y, bq.z, bq.w};
        u16x8 hv, lv;
        #pragma unroll
        for (int j = 0; j < 8; j++) { u16 hh = bf_hi(v[j]); hv[j] = hh; lv[j] = bf_hi(v[j] - bf_f(hh)); }
        *(u16x8*)(wch + (size_t)i * 8) = hv;
        *(u16x8*)(wcl + (size_t)i * 8) = lv;
    } else if (blk < 4448) {
        int g = (blk - 4192) * 256 + tid;   // (b*K+k)*C+c, 65536 total
        int kq = (g >> 8) & 63, cq = g & 255;
        float v = mu0[cq * K + kq];
        u16 hh = bf_hi(v);
        muth[g] = hh;
        mutl[g] = bf_hi(v - bf_f(hh));
    } else {
        if (tid < 40) cnt[tid] = 0;         // 36 barrier slots used
    }
}

// ================= E + M + (barrier) + norm-tail (+pmat, +mu out) =================
// grid (64, B), block 512, dynamic LDS 108,032 B -> 1 block/CU, all co-resident
__global__ __launch_bounds__(512) void k_em(
        const u16* __restrict__ xth, const u16* __restrict__ xtl,
        const u16* __restrict__ xch, const u16* __restrict__ xcl,
        u16* __restrict__ muth, u16* __restrict__ mutl,
        float* __restrict__ tpart, float* __restrict__ dpart,
        u16* __restrict__ sig_out, u16* __restrict__ Pb,
        const u16* __restrict__ wch, const u16* __restrict__ wcl,
        float* __restrict__ out_mu, u32* __restrict__ cnt,
        int iter, int pv, float dconst, int write_sig, int s_pm, int last)
{
    extern __shared__ char smem[];
    u16* smh = (u16*)smem;                  // muT hi [64][CP]
    u16* sml = smh + 64 * CP;               // muT lo
    float* slog = (float*)(sml + 64 * CP);  // partial logits [64][LGP]; tail: murow
    u16* sTh = (u16*)(slog + 64 * LGP);     // sigmaT hi [64][SP]
    u16* sTl = sTh + 64 * SP;               // sigmaT lo
    float* redf = (float*)(sTl + 64 * SP);  // 1152 floats scratch

    const int ch = blockIdx.x, b = blockIdx.y, tid = threadIdx.x;
    const int n0 = ch * 64;
    const int w = tid >> 6, l = tid & 63, lg = l >> 4, lr = l & 15;
    const int chalf = (w >> 2) * 128;
    f32x4 z4 = {0.f, 0.f, 0.f, 0.f};

    // ---- stage muT [64k][256c] hi/lo (coalesced, 8 waves) ----
    {
        size_t mbase = (size_t)(b * K) * C;
        #pragma unroll
        for (int t = tid; t < 2048; t += 512) {
            int r = t >> 5, cof = (t & 31) * 8;
            *(u16x8*)&smh[r * CP + cof] = *(const u16x8*)&muth[mbase + (size_t)r * C + cof];
            *(u16x8*)&sml[r * CP + cof] = *(const u16x8*)&mutl[mbase + (size_t)r * C + cof];
        }
    }
    // ---- x fragments into registers ----
    bf16x8 eAh[4], eAl[4];
    {
        const u16* xrh = xth + ((size_t)(b * NN + n0 + (w & 3) * 16 + lr)) * C + chalf;
        const u16* xrl = xtl + ((size_t)(b * NN + n0 + (w & 3) * 16 + lr)) * C + chalf;
        #pragma unroll
        for (int cc = 0; cc < 4; cc++) {
            eAh[cc] = *(const bf16x8*)&xrh[cc * 32 + lg * 8];
            eAl[cc] = *(const bf16x8*)&xrl[cc * 32 + lg * 8];
        }
    }
    bf16x8 mBh[4], mBl[4];
    #pragma unroll
    for (int nn2 = 0; nn2 < 2; nn2++)
        #pragma unroll
        for (int cio = 0; cio < 2; cio++) {
            int c = (w * 2 + cio) * 16 + lr;
            size_t go = ((size_t)(b * C + c)) * NN + n0 + nn2 * 32 + lg * 8;
            mBh[nn2 * 2 + cio] = *(const bf16x8*)&xch[go];
            mBl[nn2 * 2 + cio] = *(const bf16x8*)&xcl[go];
        }
    __syncthreads();

    // ---- E: logits, c-split across wave halves ----
    f32x4 acc[4] = {z4, z4, z4, z4};
    #pragma unroll
    for (int cc = 0; cc < 4; cc++) {
        int co = chalf + cc * 32 + lg * 8;
        #pragma unroll
        for (int kt = 0; kt < 4; kt++) {
            bf16x8 Bh = *(bf16x8*)&smh[(kt * 16 + lr) * CP + co];
            bf16x8 Bl = *(bf16x8*)&sml[(kt * 16 + lr) * CP + co];
            acc[kt] = __builtin_amdgcn_mfma_f32_16x16x32_bf16(eAh[cc], Bh, acc[kt], 0, 0, 0);
            acc[kt] = __builtin_amdgcn_mfma_f32_16x16x32_bf16(eAl[cc], Bh, acc[kt], 0, 0, 0);
            acc[kt] = __builtin_amdgcn_mfma_f32_16x16x32_bf16(eAh[cc], Bl, acc[kt], 0, 0, 0);
        }
    }
    if (w < 4) {
        #pragma unroll
        for (int kt = 0; kt < 4; kt++)
            #pragma unroll
            for (int jj = 0; jj < 4; jj++)
                slog[((w & 3) * 16 + lg * 4 + jj) * LGP + kt * 16 + lr] = acc[kt][jj];
    }
    __syncthreads();

    // ---- softmax + cnt weight + sigmaT pack (waves 4-7) ----
    if (w >= 4) {
        float swv[4][4];
        float psum[4] = {0.f, 0.f, 0.f, 0.f};
        #pragma unroll
        for (int jj = 0; jj < 4; jj++) {
            int rloc = (w & 3) * 16 + lg * 4 + jj;
            int n = n0 + rloc;
            float v0 = acc[0][jj] + slog[rloc * LGP + 0 * 16 + lr];
            float v1 = acc[1][jj] + slog[rloc * LGP + 1 * 16 + lr];
            float v2 = acc[2][jj] + slog[rloc * LGP + 2 * 16 + lr];
            float v3 = acc[3][jj] + slog[rloc * LGP + 3 * 16 + lr];
            float m = fmaxf(fmaxf(v0, v1), fmaxf(v2, v3));
            #pragma unroll
            for (int off = 1; off <= 8; off <<= 1) m = fmaxf(m, __shfl_xor(m, off));
            float e0 = __expf(v0 - m), e1 = __expf(v1 - m), e2 = __expf(v2 - m), e3 = __expf(v3 - m);
            float ss = e0 + e1 + e2 + e3;
            #pragma unroll
            for (int off = 1; off <= 8; off <<= 1) ss += __shfl_xor(ss, off);
            int y = n >> 6, xx = n & 63;
            float cntw = (float)((min(pv, y) + min(pv, 63 - y) + 1) * (min(pv, xx) + min(pv, 63 - xx) + 1));
            float sc = cntw / ss;
            swv[jj][0] = e0 * sc; swv[jj][1] = e1 * sc; swv[jj][2] = e2 * sc; swv[jj][3] = e3 * sc;
            #pragma unroll
            for (int kt = 0; kt < 4; kt++) {
                psum[kt] += swv[jj][kt];
                if (write_sig)
                    sig_out[((size_t)(b * NN + n)) * K + kt * 16 + lr] = bf_hi(swv[jj][kt]);
            }
        }
        #pragma unroll
        for (int kt = 0; kt < 4; kt++) {
            #pragma unroll
            for (int jp = 0; jp < 2; jp++) {
                float va = swv[2 * jp][kt], vb = swv[2 * jp + 1][kt];
                u16 ha = bf_hi(va), hb = bf_hi(vb);
                u16 la = bf_hi(va - bf_f(ha)), lb = bf_hi(vb - bf_f(hb));
                int col = (w & 3) * 16 + lg * 4 + 2 * jp;
                *(u32*)&sTh[(kt * 16 + lr) * SP + col] = (u32)ha | ((u32)hb << 16);
                *(u32*)&sTl[(kt * 16 + lr) * SP + col] = (u32)la | ((u32)lb << 16);
            }
            redf[(kt * 16 + lr) * 17 + (w & 3) * 4 + lg] = psum[kt];
        }
    }
    __syncthreads();
    if (tid < 64) {
        float sd = 0.f;
        #pragma unroll
        for (int g2 = 0; g2 < 16; g2++) sd += redf[tid * 17 + g2];
        dpart[((size_t)(b * 64 + ch)) * K + tid] = sd;
    }

    // ---- M: sigmaT(LDS) x reg B-frags -> chunked plain stores ----
    f32x4 macc[8];
    #pragma unroll
    for (int t2 = 0; t2 < 8; t2++) macc[t2] = z4;
    #pragma unroll
    for (int nn2 = 0; nn2 < 2; nn2++) {
        int no = nn2 * 32 + lg * 8;
        bf16x8 Ah[4], Al[4];
        #pragma unroll
        for (int kt2 = 0; kt2 < 4; kt2++) {
            Ah[kt2] = *(bf16x8*)&sTh[(kt2 * 16 + lr) * SP + no];
            Al[kt2] = *(bf16x8*)&sTl[(kt2 * 16 + lr) * SP + no];
        }
        #pragma unroll
        for (int cio = 0; cio < 2; cio++) {
            #pragma unroll
            for (int kt2 = 0; kt2 < 4; kt2++) {
                macc[kt2 * 2 + cio] = __builtin_amdgcn_mfma_f32_16x16x32_bf16(Ah[kt2], mBh[nn2 * 2 + cio], macc[kt2 * 2 + cio], 0, 0, 0);
                macc[kt2 * 2 + cio] = __builtin_amdgcn_mfma_f32_16x16x32_bf16(Al[kt2], mBh[nn2 * 2 + cio], macc[kt2 * 2 + cio], 0, 0, 0);
                macc[kt2 * 2 + cio] = __builtin_amdgcn_mfma_f32_16x16x32_bf16(Ah[kt2], mBl[nn2 * 2 + cio], macc[kt2 * 2 + cio], 0, 0, 0);
            }
        }
    }
    #pragma unroll
    for (int kt2 = 0; kt2 < 4; kt2++)
        #pragma unroll
        for (int cio = 0; cio < 2; cio++)
            #pragma unroll
            for (int jj = 0; jj < 4; jj++) {
                int kk = kt2 * 16 + lg * 4 + jj;
                int c = (w * 2 + cio) * 16 + lr;
                tpart[((size_t)((b * 64 + ch) * K + kk)) * C + c] = macc[kt2 * 2 + cio][jj];
            }

    // ---- per-b barrier: release fence, count 64 blocks, acquire ----
    __syncthreads();
    if (tid == 0) {
        __threadfence();
        __hip_atomic_fetch_add(&cnt[iter * B + b], 1u, __ATOMIC_ACQ_REL, __HIP_MEMORY_SCOPE_AGENT);
        while (__hip_atomic_load(&cnt[iter * B + b], __ATOMIC_ACQUIRE, __HIP_MEMORY_SCOPE_AGENT) < 64u)
            __builtin_amdgcn_s_sleep(2);
        __threadfence();
    }
    __syncthreads();

    // ---- norm-tail: this block norms k-row ch ----
    int cc2 = tid & 255, h2 = tid >> 8;
    float tt = 0.f;
    #pragma unroll 4
    for (int chn = 0; chn < 32; chn++)
        tt += tpart[((size_t)((b * 64 + h2 * 32 + chn) * K + ch)) * C + cc2];
    redf[tid] = tt;
    float dv = 0.f;
    if (tid < 64) {
        dv = dpart[((size_t)(b * 64 + tid)) * K + ch];
        #pragma unroll
        for (int off = 1; off <= 32; off <<= 1) dv += __shfl_xor(dv, off);
    }
    __syncthreads();
    float ttf = 0.f;
    if (h2 == 0) {
        ttf = redf[cc2] + redf[cc2 + 256];
        redf[512 + cc2] = ttf * ttf;
    }
    if (tid == 0) redf[1024] = dv;
    __syncthreads();
    if (tid < 64) {
        float sq = redf[512 + tid] + redf[512 + tid + 64] + redf[512 + tid + 128] + redf[512 + tid + 192];
        #pragma unroll
        for (int off = 1; off <= 32; off <<= 1) sq += __shfl_xor(sq, off);
        if (tid == 0) redf[1025] = sq;
    }
    __syncthreads();
    float d = dconst + redf[1024];
    float inv = 1.f / (1e-6f * d + sqrtf(redf[1025]));
    if (h2 == 0) {
        float v = ttf * inv;
        u16 hh = bf_hi(v);
        size_t o = ((size_t)(b * K + ch)) * C + cc2;
        muth[o] = hh;
        mutl[o] = bf_hi(v - bf_f(hh));
        if (last) out_mu[((size_t)(b * C + cc2)) * K + ch] = v;
        slog[cc2] = v;      // murow for P
    }
    __syncthreads();

    // ---- fused P-matrix column for finished scale: P[o][ch] = sum_c W[o][c]*mu[c][ch] ----
    if (s_pm >= 0) {
        const u16* wh = wch + (size_t)cc2 * W3C + s_pm * C + h2 * 128;
        const u16* wl = wcl + (size_t)cc2 * W3C + s_pm * C + h2 * 128;
        float accp = 0.f;
        #pragma unroll 4
        for (int c8 = 0; c8 < 16; c8++) {
            u16x8 hv = *(const u16x8*)&wh[c8 * 8];
            u16x8 lv = *(const u16x8*)&wl[c8 * 8];
            #pragma unroll
            for (int j = 0; j < 8; j++)
                accp += (bf_f(hv[j]) + bf_f(lv[j])) * slog[h2 * 128 + c8 * 8 + j];
        }
        redf[tid] = accp;
        __syncthreads();
        if (h2 == 0)
            Pb[((size_t)((s_pm * B + b) * C + cc2)) * K + ch] = bf_hi(redf[cc2] + redf[cc2 + 256]);
    }
}

// ================= final: out = relu(w*(sum_s sig_s P_s^T + b_cat) + x) =================
__global__ __launch_bounds__(256) void k_final(
        const u16* __restrict__ sh_g, const u16* __restrict__ Pb,
        const float* __restrict__ x, const float* __restrict__ b_cat,
        const float* __restrict__ wscal, float* __restrict__ out) {
    __shared__ u16 ssig[64 * 72];
    __shared__ u16 sP[64 * 72];
    __shared__ float tbuf[64 * 68];
    int nt = blockIdx.x, ot = blockIdx.y, b = blockIdx.z;
    int n0 = nt * 64, o0 = ot * 64;
    int tid = threadIdx.x, w = tid >> 6, l = tid & 63, lg = l >> 4, lr = l & 15;
    f32x4 z4 = {0.f, 0.f, 0.f, 0.f};
    f32x4 acc[4] = {z4, z4, z4, z4};
    for (int s = 0; s < 3; s++) {
        __syncthreads();
        for (int t = tid; t < 512; t += 256) {
            int r = t >> 3, kc = (t & 7) * 8;
            *(u16x8*)&ssig[r * 72 + kc] =
                *(const u16x8*)&sh_g[(size_t)s * ((size_t)B * NN * K) + ((size_t)(b * NN + n0 + r)) * K + kc];
            *(u16x8*)&sP[r * 72 + kc] =
                *(const u16x8*)&Pb[((size_t)((s * B + b) * C + o0 + r)) * K + kc];
        }
        __syncthreads();
        #pragma unroll
        for (int kk = 0; kk < 2; kk++) {
            int ko = kk * 32 + lg * 8;
            bf16x8 A = *(bf16x8*)&ssig[(w * 16 + lr) * 72 + ko];
            #pragma unroll
            for (int oi = 0; oi < 4; oi++) {
                bf16x8 Bv = *(bf16x8*)&sP[(oi * 16 + lr) * 72 + ko];
                acc[oi] = __builtin_amdgcn_mfma_f32_16x16x32_bf16(A, Bv, acc[oi], 0, 0, 0);
            }
        }
    }
    __syncthreads();
    #pragma unroll
    for (int oi = 0; oi < 4; oi++)
        #pragma unroll
        for (int jj = 0; jj < 4; jj++)
            tbuf[(oi * 16 + lr) * 68 + (w * 16 + lg * 4 + jj)] = acc[oi][jj];
    __syncthreads();
    float wv = wscal[0];
    for (int t = tid; t < 1024; t += 256) {
        int ol = t >> 4, ck = (t & 15) * 4;
        int o = o0 + ol;
        float bc = b_cat[o];
        float4 u4 = *(float4*)&tbuf[ol * 68 + ck];
        size_t base = ((size_t)(b * C + o)) * NN + n0 + ck;
        float4 xv = *(const float4*)&x[base];
        float4 r;
        r.x = fmaxf((u4.x + bc) * wv + xv.x, 0.f);
        r.y = fmaxf((u4.y + bc) * wv + xv.y, 0.f);
        r.z = fmaxf((u4.z + bc) * wv + xv.z, 0.f);
        r.w = fmaxf((u4.w + bc) * wv + xv.w, 0.f);
        *(float4*)&out[base] = r;
    }
}

extern "C" void kernel_launch(void* const* d_in, const int* in_sizes, int n_in,
                              void* d_out, int out_size, void* d_ws, size_t ws_size,
                              hipStream_t stream) {
    const float* x     = (const float*)d_in[0];
    const float* mu0   = (const float*)d_in[1];
    const float* wsc   = (const float*)d_in[2];
    const float* w_cat = (const float*)d_in[3];
    const float* b_cat = (const float*)d_in[4];
    float* out = (float*)d_out;
    char* wsb = (char*)d_ws;

    const size_t SZ_X2   = (size_t)B * C * NN * 2;     // 8 MB
    const size_t SZ_MUT  = (size_t)B * K * C * 2;      // 128 KB
    const size_t SZ_SIGH = (size_t)3 * B * NN * K * 2; // 6 MB
    const size_t SZ_TP   = (size_t)B * 64 * K * C * 4; // 16 MB
    const size_t SZ_DP   = (size_t)B * 64 * K * 4;     // 64 KB
    const size_t SZ_PB   = (size_t)3 * B * C * K * 2;  // 384 KB
    const size_t SZ_WC   = (size_t)C * W3C * 2;        // 384 KB

    size_t off = 0;
    u16*   xch  = (u16*)(wsb + off); off += SZ_X2;
    u16*   xcl  = (u16*)(wsb + off); off += SZ_X2;
    u16*   xth  = (u16*)(wsb + off); off += SZ_X2;
    u16*   xtl  = (u16*)(wsb + off); off += SZ_X2;
    u16*   muth = (u16*)(wsb + off); off += SZ_MUT;
    u16*   mutl = (u16*)(wsb + off); off += SZ_MUT;
    u16*   sigh = (u16*)(wsb + off); off += SZ_SIGH;
    float* tpart= (float*)(wsb + off); off += SZ_TP;
    float* dpart= (float*)(wsb + off); off += SZ_DP;
    u16*   Pb   = (u16*)(wsb + off); off += SZ_PB;
    u16*   wch  = (u16*)(wsb + off); off += SZ_WC;
    u16*   wcl  = (u16*)(wsb + off); off += SZ_WC;
    u32*   cnt  = (u32*)(wsb + off); off += 256;
    float* out_mu = out + (size_t)B * C * NN;

    const int EM_LDS = 2 * 64 * CP * 2 + 64 * LGP * 4 + 2 * 64 * SP * 2 + 1152 * 4; // 108,032
    hipFuncSetAttribute((const void*)k_em, hipFuncAttributeMaxDynamicSharedMemorySize, EM_LDS);

    k_prep<<<4449, 256, 0, stream>>>(x, mu0, w_cat, xch, xcl, xth, xtl,
                                     wch, wcl, muth, mutl, cnt);

    const float dconsts[3] = {1e-6f, 1e-6f + 11.9375f, 1e-6f + 59.4375f};

    for (int i = 0; i < 9; i++) {
        int s = i / 3;
        u16* shs = sigh + (size_t)s * ((size_t)B * NN * K);
        k_em<<<dim3(64, B), 512, EM_LDS, stream>>>(
            xth, xtl, xch, xcl, muth, mutl, tpart, dpart, shs, Pb, wch, wcl,
            out_mu, cnt,
            i, s, dconsts[s], (i % 3 == 2) ? 1 : 0, (i % 3 == 2) ? s : -1,
            (i == 8) ? 1 : 0);
    }
    k_final<<<dim3(64, 4, B), 256, 0, stream>>>(sigh, Pb, x, b_cat, wsc, out);
}

// Round 11
// 298.057 us; speedup vs baseline: 1.8286x; 1.8286x over previous
//
#include <hip/hip_runtime.h>

typedef float f32x4 __attribute__((ext_vector_type(4)));
typedef short bf16x8 __attribute__((ext_vector_type(8)));
typedef unsigned short u16;
typedef u16 u16x8 __attribute__((ext_vector_type(8)));
typedef unsigned int u32;

#define B 4
#define C 256
#define K 64
#define NN 4096
#define W3C 768
#define SP 72    // sigmaT LDS pitch (shorts)
#define LGP 68   // logits LDS pitch (floats)

__device__ __forceinline__ u16 bf_hi(float f) {
    unsigned u = __float_as_uint(f);
    u += 0x7FFFu + ((u >> 16) & 1u);
    return (u16)(u >> 16);
}
__device__ __forceinline__ float bf_f(u16 s) { return __uint_as_float(((unsigned)s) << 16); }

// ================= merged prep: single x read -> both layouts; w_cat; mu =================
// grid 4448 x 256
__global__ void k_prep(const float* __restrict__ x, const float* __restrict__ mu0,
                       const float* __restrict__ w_cat,
                       u16* __restrict__ xch, u16* __restrict__ xcl,
                       u16* __restrict__ xth, u16* __restrict__ xtl,
                       u16* __restrict__ wch, u16* __restrict__ wcl,
                       u16* __restrict__ muth, u16* __restrict__ mutl) {
    __shared__ float tile[32][33];
    int blk = blockIdx.x, tid = threadIdx.x;
    if (blk < 4096) {
        // 32x32 tile of x: emit transposed (xth/xtl) AND c-major (xch/xcl) bf16 hi/lo
        int b2 = blk >> 10, rem = blk & 1023;
        int c0 = (rem >> 7) << 5, m0 = (rem & 127) << 5;
        int tx = tid & 31, ty = tid >> 5;   // ty in 0..7
        #pragma unroll
        for (int j = 0; j < 4; j++)
            tile[ty + j * 8][tx] = x[((size_t)(b2 * C + c0 + ty + j * 8)) * NN + m0 + tx];
        __syncthreads();
        #pragma unroll
        for (int j = 0; j < 4; j++) {
            // c-major: row c = c0+ty+j*8, col n = m0+tx
            float vc = tile[ty + j * 8][tx];
            u16 hc = bf_hi(vc);
            size_t oc = ((size_t)(b2 * C + c0 + ty + j * 8)) * NN + m0 + tx;
            xch[oc] = hc;
            xcl[oc] = bf_hi(vc - bf_f(hc));
            // n-major: row n = m0+ty+j*8, col c = c0+tx
            float vt = tile[tx][ty + j * 8];
            u16 ht = bf_hi(vt);
            size_t ot = ((size_t)(b2 * NN + m0 + ty + j * 8)) * C + c0 + tx;
            xth[ot] = ht;
            xtl[ot] = bf_hi(vt - bf_f(ht));
        }
    } else if (blk < 4192) {
        int i = (blk - 4096) * 256 + tid;   // 96 blocks x 256 = 24576 = C*W3C/8
        const float4* s4 = (const float4*)(w_cat + (size_t)i * 8);
        float4 a = s4[0], bq = s4[1];
        float v[8] = {a.x, a.y, a.z, a.w, bq.x, bq.y, bq.z, bq.w};
        u16x8 hv, lv;
        #pragma unroll
        for (int j = 0; j < 8; j++) { u16 hh = bf_hi(v[j]); hv[j] = hh; lv[j] = bf_hi(v[j] - bf_f(hh)); }
        *(u16x8*)(wch + (size_t)i * 8) = hv;
        *(u16x8*)(wcl + (size_t)i * 8) = lv;
    } else {
        int g = (blk - 4192) * 256 + tid;   // (b*K+k)*C+c, 65536 total
        int kq = (g >> 8) & 63, cq = g & 255;
        float v = mu0[cq * K + kq];
        u16 hh = bf_hi(v);
        muth[g] = hh;
        mutl[g] = bf_hi(v - bf_f(hh));
    }
}

// ================= E + M step (512 thr, direct-global muT frags, no staging) =================
// grid (64, B), block 512, dynamic LDS 40,448 B
__global__ __launch_bounds__(512) void k_em(
        const u16* __restrict__ xth, const u16* __restrict__ xtl,
        const u16* __restrict__ xch, const u16* __restrict__ xcl,
        const u16* __restrict__ muth, const u16* __restrict__ mutl,
        float* __restrict__ tpart, float* __restrict__ dpart,
        u16* __restrict__ sig_out, int pv, int write_sig)
{
    extern __shared__ char smem[];
    float* slog = (float*)smem;             // partial logits [64][LGP]
    u16* sTh = (u16*)(slog + 64 * LGP);     // sigmaT hi [64][SP]
    u16* sTl = sTh + 64 * SP;               // sigmaT lo
    float* redf = (float*)(sTl + 64 * SP);  // scratch

    const int ch = blockIdx.x, b = blockIdx.y, tid = threadIdx.x;
    const int n0 = ch * 64;
    const int w = tid >> 6, l = tid & 63, lg = l >> 4, lr = l & 15;
    const int chalf = (w >> 2) * 128;
    f32x4 z4 = {0.f, 0.f, 0.f, 0.f};

    // ---- x fragments into registers ----
    bf16x8 eAh[4], eAl[4];
    {
        const u16* xrh = xth + ((size_t)(b * NN + n0 + (w & 3) * 16 + lr)) * C + chalf;
        const u16* xrl = xtl + ((size_t)(b * NN + n0 + (w & 3) * 16 + lr)) * C + chalf;
        #pragma unroll
        for (int cc = 0; cc < 4; cc++) {
            eAh[cc] = *(const bf16x8*)&xrh[cc * 32 + lg * 8];
            eAl[cc] = *(const bf16x8*)&xrl[cc * 32 + lg * 8];
        }
    }
    bf16x8 mBh[4], mBl[4];
    #pragma unroll
    for (int nn2 = 0; nn2 < 2; nn2++)
        #pragma unroll
        for (int cio = 0; cio < 2; cio++) {
            int c = (w * 2 + cio) * 16 + lr;
            size_t go = ((size_t)(b * C + c)) * NN + n0 + nn2 * 32 + lg * 8;
            mBh[nn2 * 2 + cio] = *(const bf16x8*)&xch[go];
            mBl[nn2 * 2 + cio] = *(const bf16x8*)&xcl[go];
        }

    // ---- E: logits, c-split across wave halves; muT B-frags DIRECT from global ----
    f32x4 acc[4] = {z4, z4, z4, z4};
    {
        const u16* mrh = muth + ((size_t)(b * K + lr)) * C + chalf;
        const u16* mrl = mutl + ((size_t)(b * K + lr)) * C + chalf;
        #pragma unroll
        for (int cc = 0; cc < 4; cc++) {
            int co = cc * 32 + lg * 8;
            #pragma unroll
            for (int kt = 0; kt < 4; kt++) {
                bf16x8 Bh = *(const bf16x8*)&mrh[(size_t)(kt * 16) * C + co];
                bf16x8 Bl = *(const bf16x8*)&mrl[(size_t)(kt * 16) * C + co];
                acc[kt] = __builtin_amdgcn_mfma_f32_16x16x32_bf16(eAh[cc], Bh, acc[kt], 0, 0, 0);
                acc[kt] = __builtin_amdgcn_mfma_f32_16x16x32_bf16(eAl[cc], Bh, acc[kt], 0, 0, 0);
                acc[kt] = __builtin_amdgcn_mfma_f32_16x16x32_bf16(eAh[cc], Bl, acc[kt], 0, 0, 0);
            }
        }
    }
    if (w < 4) {
        #pragma unroll
        for (int kt = 0; kt < 4; kt++)
            #pragma unroll
            for (int jj = 0; jj < 4; jj++)
                slog[((w & 3) * 16 + lg * 4 + jj) * LGP + kt * 16 + lr] = acc[kt][jj];
    }
    __syncthreads();

    // ---- softmax + cnt weight + sigmaT pack (waves 4-7) ----
    if (w >= 4) {
        float swv[4][4];
        float psum[4] = {0.f, 0.f, 0.f, 0.f};
        #pragma unroll
        for (int jj = 0; jj < 4; jj++) {
            int rloc = (w & 3) * 16 + lg * 4 + jj;
            int n = n0 + rloc;
            float v0 = acc[0][jj] + slog[rloc * LGP + 0 * 16 + lr];
            float v1 = acc[1][jj] + slog[rloc * LGP + 1 * 16 + lr];
            float v2 = acc[2][jj] + slog[rloc * LGP + 2 * 16 + lr];
            float v3 = acc[3][jj] + slog[rloc * LGP + 3 * 16 + lr];
            float m = fmaxf(fmaxf(v0, v1), fmaxf(v2, v3));
            #pragma unroll
            for (int off = 1; off <= 8; off <<= 1) m = fmaxf(m, __shfl_xor(m, off));
            float e0 = __expf(v0 - m), e1 = __expf(v1 - m), e2 = __expf(v2 - m), e3 = __expf(v3 - m);
            float ss = e0 + e1 + e2 + e3;
            #pragma unroll
            for (int off = 1; off <= 8; off <<= 1) ss += __shfl_xor(ss, off);
            int y = n >> 6, xx = n & 63;
            float cntw = (float)((min(pv, y) + min(pv, 63 - y) + 1) * (min(pv, xx) + min(pv, 63 - xx) + 1));
            float sc = cntw / ss;
            swv[jj][0] = e0 * sc; swv[jj][1] = e1 * sc; swv[jj][2] = e2 * sc; swv[jj][3] = e3 * sc;
            #pragma unroll
            for (int kt = 0; kt < 4; kt++) {
                psum[kt] += swv[jj][kt];
                if (write_sig)
                    sig_out[((size_t)(b * NN + n)) * K + kt * 16 + lr] = bf_hi(swv[jj][kt]);
            }
        }
        #pragma unroll
        for (int kt = 0; kt < 4; kt++) {
            #pragma unroll
            for (int jp = 0; jp < 2; jp++) {
                float va = swv[2 * jp][kt], vb = swv[2 * jp + 1][kt];
                u16 ha = bf_hi(va), hb = bf_hi(vb);
                u16 la = bf_hi(va - bf_f(ha)), lb = bf_hi(vb - bf_f(hb));
                int col = (w & 3) * 16 + lg * 4 + 2 * jp;
                *(u32*)&sTh[(kt * 16 + lr) * SP + col] = (u32)ha | ((u32)hb << 16);
                *(u32*)&sTl[(kt * 16 + lr) * SP + col] = (u32)la | ((u32)lb << 16);
            }
            redf[(kt * 16 + lr) * 17 + (w & 3) * 4 + lg] = psum[kt];
        }
    }
    __syncthreads();
    if (tid < 64) {
        float sd = 0.f;
        #pragma unroll
        for (int g2 = 0; g2 < 16; g2++) sd += redf[tid * 17 + g2];
        dpart[((size_t)(b * 64 + ch)) * K + tid] = sd;
    }

    // ---- M: sigmaT(LDS) x reg B-frags -> chunked plain stores ----
    f32x4 macc[8];
    #pragma unroll
    for (int t2 = 0; t2 < 8; t2++) macc[t2] = z4;
    #pragma unroll
    for (int nn2 = 0; nn2 < 2; nn2++) {
        int no = nn2 * 32 + lg * 8;
        bf16x8 Ah[4], Al[4];
        #pragma unroll
        for (int kt2 = 0; kt2 < 4; kt2++) {
            Ah[kt2] = *(bf16x8*)&sTh[(kt2 * 16 + lr) * SP + no];
            Al[kt2] = *(bf16x8*)&sTl[(kt2 * 16 + lr) * SP + no];
        }
        #pragma unroll
        for (int cio = 0; cio < 2; cio++) {
            #pragma unroll
            for (int kt2 = 0; kt2 < 4; kt2++) {
                macc[kt2 * 2 + cio] = __builtin_amdgcn_mfma_f32_16x16x32_bf16(Ah[kt2], mBh[nn2 * 2 + cio], macc[kt2 * 2 + cio], 0, 0, 0);
                macc[kt2 * 2 + cio] = __builtin_amdgcn_mfma_f32_16x16x32_bf16(Al[kt2], mBh[nn2 * 2 + cio], macc[kt2 * 2 + cio], 0, 0, 0);
                macc[kt2 * 2 + cio] = __builtin_amdgcn_mfma_f32_16x16x32_bf16(Ah[kt2], mBl[nn2 * 2 + cio], macc[kt2 * 2 + cio], 0, 0, 0);
            }
        }
    }
    #pragma unroll
    for (int kt2 = 0; kt2 < 4; kt2++)
        #pragma unroll
        for (int cio = 0; cio < 2; cio++)
            #pragma unroll
            for (int jj = 0; jj < 4; jj++) {
                int kk = kt2 * 16 + lg * 4 + jj;
                int c = (w * 2 + cio) * 16 + lr;
                tpart[((size_t)((b * 64 + ch) * K + kk)) * C + c] = macc[kt2 * 2 + cio][jj];
            }
}

// ================= reduce + l2norm -> muT (+ fused pmat, + mu output) =================
// grid (K, B), block 256 (tid = c, and tid = o for pmat)
__global__ __launch_bounds__(256) void k_norm(
        const float* __restrict__ tpart, const float* __restrict__ dpart,
        u16* __restrict__ muth, u16* __restrict__ mutl,
        u16* __restrict__ Pb, const u16* __restrict__ wch, const u16* __restrict__ wcl,
        float* __restrict__ out_mu, float dconst, int s_pm, int last) {
    __shared__ float red[256];
    __shared__ float murow[256];
    __shared__ float dsh;
    int k = blockIdx.x, b = blockIdx.y, tid = threadIdx.x;
    float dv = 0.f;
    if (tid < 64) dv = dpart[((size_t)(b * 64 + tid)) * K + k];
    #pragma unroll
    for (int off = 1; off <= 32; off <<= 1) dv += __shfl_xor(dv, off);
    if (tid == 0) dsh = dv;
    float tt = 0.f;
    #pragma unroll 8
    for (int chn = 0; chn < 64; chn++)
        tt += tpart[((size_t)((b * 64 + chn) * K + k)) * C + tid];
    red[tid] = tt * tt;
    __syncthreads();
    for (int st = 128; st > 0; st >>= 1) {
        if (tid < st) red[tid] += red[tid + st];
        __syncthreads();
    }
    float d = dconst + dsh;
    float inv = 1.f / (1e-6f * d + sqrtf(red[0]));
    float v = tt * inv;
    murow[tid] = v;
    u16 hh = bf_hi(v);
    size_t o = ((size_t)(b * K + k)) * C + tid;
    muth[o] = hh;
    mutl[o] = bf_hi(v - bf_f(hh));
    if (last) out_mu[((size_t)(b * C + tid)) * K + k] = v;
    if (s_pm >= 0) {
        __syncthreads();
        const u16* wh = wch + (size_t)tid * W3C + s_pm * C;
        const u16* wl = wcl + (size_t)tid * W3C + s_pm * C;
        float accp = 0.f;
        #pragma unroll 4
        for (int c8 = 0; c8 < 32; c8++) {
            u16x8 hv = *(const u16x8*)&wh[c8 * 8];
            u16x8 lv = *(const u16x8*)&wl[c8 * 8];
            #pragma unroll
            for (int j = 0; j < 8; j++)
                accp += (bf_f(hv[j]) + bf_f(lv[j])) * murow[c8 * 8 + j];
        }
        Pb[((size_t)((s_pm * B + b) * C + tid)) * K + k] = bf_hi(accp);
    }
}

// ================= final: out = relu(w*(sum_s sig_s P_s^T + b_cat) + x) =================
__global__ __launch_bounds__(256) void k_final(
        const u16* __restrict__ sh_g, const u16* __restrict__ Pb,
        const float* __restrict__ x, const float* __restrict__ b_cat,
        const float* __restrict__ wscal, float* __restrict__ out) {
    __shared__ u16 ssig[64 * 72];
    __shared__ u16 sP[64 * 72];
    __shared__ float tbuf[64 * 68];
    int nt = blockIdx.x, ot = blockIdx.y, b = blockIdx.z;
    int n0 = nt * 64, o0 = ot * 64;
    int tid = threadIdx.x, w = tid >> 6, l = tid & 63, lg = l >> 4, lr = l & 15;
    f32x4 z4 = {0.f, 0.f, 0.f, 0.f};
    f32x4 acc[4] = {z4, z4, z4, z4};
    for (int s = 0; s < 3; s++) {
        __syncthreads();
        for (int t = tid; t < 512; t += 256) {
            int r = t >> 3, kc = (t & 7) * 8;
            *(u16x8*)&ssig[r * 72 + kc] =
                *(const u16x8*)&sh_g[(size_t)s * ((size_t)B * NN * K) + ((size_t)(b * NN + n0 + r)) * K + kc];
            *(u16x8*)&sP[r * 72 + kc] =
                *(const u16x8*)&Pb[((size_t)((s * B + b) * C + o0 + r)) * K + kc];
        }
        __syncthreads();
        #pragma unroll
        for (int kk = 0; kk < 2; kk++) {
            int ko = kk * 32 + lg * 8;
            bf16x8 A = *(bf16x8*)&ssig[(w * 16 + lr) * 72 + ko];
            #pragma unroll
            for (int oi = 0; oi < 4; oi++) {
                bf16x8 Bv = *(bf16x8*)&sP[(oi * 16 + lr) * 72 + ko];
                acc[oi] = __builtin_amdgcn_mfma_f32_16x16x32_bf16(A, Bv, acc[oi], 0, 0, 0);
            }
        }
    }
    __syncthreads();
    #pragma unroll
    for (int oi = 0; oi < 4; oi++)
        #pragma unroll
        for (int jj = 0; jj < 4; jj++)
            tbuf[(oi * 16 + lr) * 68 + (w * 16 + lg * 4 + jj)] = acc[oi][jj];
    __syncthreads();
    float wv = wscal[0];
    for (int t = tid; t < 1024; t += 256) {
        int ol = t >> 4, ck = (t & 15) * 4;
        int o = o0 + ol;
        float bc = b_cat[o];
        float4 u4 = *(float4*)&tbuf[ol * 68 + ck];
        size_t base = ((size_t)(b * C + o)) * NN + n0 + ck;
        float4 xv = *(const float4*)&x[base];
        float4 r;
        r.x = fmaxf((u4.x + bc) * wv + xv.x, 0.f);
        r.y = fmaxf((u4.y + bc) * wv + xv.y, 0.f);
        r.z = fmaxf((u4.z + bc) * wv + xv.z, 0.f);
        r.w = fmaxf((u4.w + bc) * wv + xv.w, 0.f);
        *(float4*)&out[base] = r;
    }
}

extern "C" void kernel_launch(void* const* d_in, const int* in_sizes, int n_in,
                              void* d_out, int out_size, void* d_ws, size_t ws_size,
                              hipStream_t stream) {
    const float* x     = (const float*)d_in[0];
    const float* mu0   = (const float*)d_in[1];
    const float* wsc   = (const float*)d_in[2];
    const float* w_cat = (const float*)d_in[3];
    const float* b_cat = (const float*)d_in[4];
    float* out = (float*)d_out;
    char* wsb = (char*)d_ws;

    const size_t SZ_X2   = (size_t)B * C * NN * 2;     // 8 MB
    const size_t SZ_MUT  = (size_t)B * K * C * 2;      // 128 KB
    const size_t SZ_SIGH = (size_t)3 * B * NN * K * 2; // 6 MB
    const size_t SZ_TP   = (size_t)B * 64 * K * C * 4; // 16 MB
    const size_t SZ_DP   = (size_t)B * 64 * K * 4;     // 64 KB
    const size_t SZ_PB   = (size_t)3 * B * C * K * 2;  // 384 KB
    const size_t SZ_WC   = (size_t)C * W3C * 2;        // 384 KB

    size_t off = 0;
    u16*   xch  = (u16*)(wsb + off); off += SZ_X2;
    u16*   xcl  = (u16*)(wsb + off); off += SZ_X2;
    u16*   xth  = (u16*)(wsb + off); off += SZ_X2;
    u16*   xtl  = (u16*)(wsb + off); off += SZ_X2;
    u16*   muth = (u16*)(wsb + off); off += SZ_MUT;
    u16*   mutl = (u16*)(wsb + off); off += SZ_MUT;
    u16*   sigh = (u16*)(wsb + off); off += SZ_SIGH;
    float* tpart= (float*)(wsb + off); off += SZ_TP;
    float* dpart= (float*)(wsb + off); off += SZ_DP;
    u16*   Pb   = (u16*)(wsb + off); off += SZ_PB;
    u16*   wch  = (u16*)(wsb + off); off += SZ_WC;
    u16*   wcl  = (u16*)(wsb + off); off += SZ_WC;
    float* out_mu = out + (size_t)B * C * NN;

    const int EM_LDS = 64 * LGP * 4 + 2 * 64 * SP * 2 + 1152 * 4;  // 40,448
    hipFuncSetAttribute((const void*)k_em, hipFuncAttributeMaxDynamicSharedMemorySize, EM_LDS);

    k_prep<<<4448, 256, 0, stream>>>(x, mu0, w_cat, xch, xcl, xth, xtl,
                                     wch, wcl, muth, mutl);

    const float dconsts[3] = {1e-6f, 1e-6f + 11.9375f, 1e-6f + 59.4375f};

    for (int i = 0; i < 9; i++) {
        int s = i / 3;
        u16* shs = sigh + (size_t)s * ((size_t)B * NN * K);
        k_em<<<dim3(64, B), 512, EM_LDS, stream>>>(
            xth, xtl, xch, xcl, muth, mutl, tpart, dpart, shs, s, (i % 3 == 2) ? 1 : 0);
        k_norm<<<dim3(K, B), 256, 0, stream>>>(
            tpart, dpart, muth, mutl, Pb, wch, wcl, out_mu,
            dconsts[s], (i % 3 == 2) ? s : -1, (i == 8) ? 1 : 0);
    }
    k_final<<<dim3(64, 4, B), 256, 0, stream>>>(sigh, Pb, x, b_cat, wsc, out);
}

// Round 12
// 259.356 us; speedup vs baseline: 2.1014x; 1.1492x over previous
//
#include <hip/hip_runtime.h>

typedef float f32x4 __attribute__((ext_vector_type(4)));
typedef short bf16x8 __attribute__((ext_vector_type(8)));
typedef unsigned short u16;
typedef u16 u16x8 __attribute__((ext_vector_type(8)));
typedef unsigned int u32;

#define B 4
#define C 256
#define K 64
#define NN 4096
#define W3C 768
#define CP 264   // muT LDS pitch (shorts)
#define SP 72    // sigmaT LDS pitch (shorts)
#define LGP 68   // logits LDS pitch (floats)

__device__ __forceinline__ u16 bf_hi(float f) {
    unsigned u = __float_as_uint(f);
    u += 0x7FFFu + ((u >> 16) & 1u);
    return (u16)(u >> 16);
}
__device__ __forceinline__ float bf_f(u16 s) { return __uint_as_float(((unsigned)s) << 16); }

// ================= merged prep: x->hi/lo, w_cat->hi/lo, mu init, transpose =================
// grid 6496 x 256
__global__ void k_prep(const float* __restrict__ x, const float* __restrict__ mu0,
                       const float* __restrict__ w_cat,
                       u16* __restrict__ xch, u16* __restrict__ xcl,
                       u16* __restrict__ wch, u16* __restrict__ wcl,
                       u16* __restrict__ muth, u16* __restrict__ mutl,
                       u16* __restrict__ xth, u16* __restrict__ xtl) {
    __shared__ float tile[32][33];
    int blk = blockIdx.x, tid = threadIdx.x;
    if (blk < 2048) {
        int i = blk * 256 + tid;
        const float4* s4 = (const float4*)(x + (size_t)i * 8);
        float4 a = s4[0], bq = s4[1];
        float v[8] = {a.x, a.y, a.z, a.w, bq.x, bq.y, bq.z, bq.w};
        u16x8 hv, lv;
        #pragma unroll
        for (int j = 0; j < 8; j++) { u16 hh = bf_hi(v[j]); hv[j] = hh; lv[j] = bf_hi(v[j] - bf_f(hh)); }
        *(u16x8*)(xch + (size_t)i * 8) = hv;
        *(u16x8*)(xcl + (size_t)i * 8) = lv;
    } else if (blk < 2144) {
        int i = (blk - 2048) * 256 + tid;
        const float4* s4 = (const float4*)(w_cat + (size_t)i * 8);
        float4 a = s4[0], bq = s4[1];
        float v[8] = {a.x, a.y, a.z, a.w, bq.x, bq.y, bq.z, bq.w};
        u16x8 hv, lv;
        #pragma unroll
        for (int j = 0; j < 8; j++) { u16 hh = bf_hi(v[j]); hv[j] = hh; lv[j] = bf_hi(v[j] - bf_f(hh)); }
        *(u16x8*)(wch + (size_t)i * 8) = hv;
        *(u16x8*)(wcl + (size_t)i * 8) = lv;
    } else if (blk < 2400) {
        int g = (blk - 2144) * 256 + tid;   // (b*K+k)*C+c
        int kq = (g >> 8) & 63, cq = g & 255;
        float v = mu0[cq * K + kq];
        u16 hh = bf_hi(v);
        muth[g] = hh;
        mutl[g] = bf_hi(v - bf_f(hh));
    } else {
        int t = blk - 2400;                 // 4096 transpose tiles (32x32)
        int b2 = t >> 10, rem = t & 1023;
        int c0 = (rem >> 7) << 5, m0 = (rem & 127) << 5;
        int tx = tid & 31, ty = tid >> 5;
        #pragma unroll
        for (int j = 0; j < 4; j++)
            tile[ty + j * 8][tx] = x[((size_t)(b2 * C + c0 + ty + j * 8)) * NN + m0 + tx];
        __syncthreads();
        #pragma unroll
        for (int j = 0; j < 4; j++) {
            int n = m0 + ty + j * 8;
            float v = tile[tx][ty + j * 8];
            u16 hh = bf_hi(v);
            size_t o = ((size_t)(b2 * NN + n)) * C + c0 + tx;
            xth[o] = hh;
            xtl[o] = bf_hi(v - bf_f(hh));
        }
    }
}

// ================= E + M step (512 thr, plain stores, no atomics) =================
// grid (64, B), block 512, dynamic LDS 108,032 B
__global__ __launch_bounds__(512) void k_em(
        const u16* __restrict__ xth, const u16* __restrict__ xtl,
        const u16* __restrict__ xch, const u16* __restrict__ xcl,
        const u16* __restrict__ muth, const u16* __restrict__ mutl,
        float* __restrict__ tpart, float* __restrict__ dpart,
        u16* __restrict__ sig_out, int pv, int write_sig)
{
    extern __shared__ char smem[];
    u16* smh = (u16*)smem;                  // muT hi [64][CP]
    u16* sml = smh + 64 * CP;               // muT lo
    float* slog = (float*)(sml + 64 * CP);  // partial logits [64][LGP]
    u16* sTh = (u16*)(slog + 64 * LGP);     // sigmaT hi [64][SP]
    u16* sTl = sTh + 64 * SP;               // sigmaT lo
    float* redf = (float*)(sTl + 64 * SP);  // scratch

    const int ch = blockIdx.x, b = blockIdx.y, tid = threadIdx.x;
    const int n0 = ch * 64;
    const int w = tid >> 6, l = tid & 63, lg = l >> 4, lr = l & 15;
    const int chalf = (w >> 2) * 128;
    f32x4 z4 = {0.f, 0.f, 0.f, 0.f};

    // ---- stage muT [64k][256c] hi/lo (coalesced, 8 waves) ----
    {
        size_t mbase = (size_t)(b * K) * C;
        #pragma unroll
        for (int t = tid; t < 2048; t += 512) {
            int r = t >> 5, cof = (t & 31) * 8;
            *(u16x8*)&smh[r * CP + cof] = *(const u16x8*)&muth[mbase + (size_t)r * C + cof];
            *(u16x8*)&sml[r * CP + cof] = *(const u16x8*)&mutl[mbase + (size_t)r * C + cof];
        }
    }
    // ---- x fragments into registers (independent of LDS; overlaps staging) ----
    bf16x8 eAh[4], eAl[4];
    {
        const u16* xrh = xth + ((size_t)(b * NN + n0 + (w & 3) * 16 + lr)) * C + chalf;
        const u16* xrl = xtl + ((size_t)(b * NN + n0 + (w & 3) * 16 + lr)) * C + chalf;
        #pragma unroll
        for (int cc = 0; cc < 4; cc++) {
            eAh[cc] = *(const bf16x8*)&xrh[cc * 32 + lg * 8];
            eAl[cc] = *(const bf16x8*)&xrl[cc * 32 + lg * 8];
        }
    }
    bf16x8 mBh[4], mBl[4];
    #pragma unroll
    for (int nn2 = 0; nn2 < 2; nn2++)
        #pragma unroll
        for (int cio = 0; cio < 2; cio++) {
            int c = (w * 2 + cio) * 16 + lr;
            size_t go = ((size_t)(b * C + c)) * NN + n0 + nn2 * 32 + lg * 8;
            mBh[nn2 * 2 + cio] = *(const bf16x8*)&xch[go];
            mBl[nn2 * 2 + cio] = *(const bf16x8*)&xcl[go];
        }
    __syncthreads();

    // ---- E: logits, c-split across wave halves ----
    f32x4 acc[4] = {z4, z4, z4, z4};
    #pragma unroll
    for (int cc = 0; cc < 4; cc++) {
        int co = chalf + cc * 32 + lg * 8;
        #pragma unroll
        for (int kt = 0; kt < 4; kt++) {
            bf16x8 Bh = *(bf16x8*)&smh[(kt * 16 + lr) * CP + co];
            bf16x8 Bl = *(bf16x8*)&sml[(kt * 16 + lr) * CP + co];
            acc[kt] = __builtin_amdgcn_mfma_f32_16x16x32_bf16(eAh[cc], Bh, acc[kt], 0, 0, 0);
            acc[kt] = __builtin_amdgcn_mfma_f32_16x16x32_bf16(eAl[cc], Bh, acc[kt], 0, 0, 0);
            acc[kt] = __builtin_amdgcn_mfma_f32_16x16x32_bf16(eAh[cc], Bl, acc[kt], 0, 0, 0);
        }
    }
    if (w < 4) {
        #pragma unroll
        for (int kt = 0; kt < 4; kt++)
            #pragma unroll
            for (int jj = 0; jj < 4; jj++)
                slog[((w & 3) * 16 + lg * 4 + jj) * LGP + kt * 16 + lr] = acc[kt][jj];
    }
    __syncthreads();

    // ---- softmax + cnt weight + sigmaT pack (waves 4-7) ----
    if (w >= 4) {
        float swv[4][4];
        float psum[4] = {0.f, 0.f, 0.f, 0.f};
        #pragma unroll
        for (int jj = 0; jj < 4; jj++) {
            int rloc = (w & 3) * 16 + lg * 4 + jj;
            int n = n0 + rloc;
            float v0 = acc[0][jj] + slog[rloc * LGP + 0 * 16 + lr];
            float v1 = acc[1][jj] + slog[rloc * LGP + 1 * 16 + lr];
            float v2 = acc[2][jj] + slog[rloc * LGP + 2 * 16 + lr];
            float v3 = acc[3][jj] + slog[rloc * LGP + 3 * 16 + lr];
            float m = fmaxf(fmaxf(v0, v1), fmaxf(v2, v3));
            #pragma unroll
            for (int off = 1; off <= 8; off <<= 1) m = fmaxf(m, __shfl_xor(m, off));
            float e0 = __expf(v0 - m), e1 = __expf(v1 - m), e2 = __expf(v2 - m), e3 = __expf(v3 - m);
            float ss = e0 + e1 + e2 + e3;
            #pragma unroll
            for (int off = 1; off <= 8; off <<= 1) ss += __shfl_xor(ss, off);
            int y = n >> 6, xx = n & 63;
            float cntw = (float)((min(pv, y) + min(pv, 63 - y) + 1) * (min(pv, xx) + min(pv, 63 - xx) + 1));
            float sc = cntw / ss;
            swv[jj][0] = e0 * sc; swv[jj][1] = e1 * sc; swv[jj][2] = e2 * sc; swv[jj][3] = e3 * sc;
            #pragma unroll
            for (int kt = 0; kt < 4; kt++) {
                psum[kt] += swv[jj][kt];
                if (write_sig)
                    sig_out[((size_t)(b * NN + n)) * K + kt * 16 + lr] = bf_hi(swv[jj][kt]);
            }
        }
        #pragma unroll
        for (int kt = 0; kt < 4; kt++) {
            #pragma unroll
            for (int jp = 0; jp < 2; jp++) {
                float va = swv[2 * jp][kt], vb = swv[2 * jp + 1][kt];
                u16 ha = bf_hi(va), hb = bf_hi(vb);
                u16 la = bf_hi(va - bf_f(ha)), lb = bf_hi(vb - bf_f(hb));
                int col = (w & 3) * 16 + lg * 4 + 2 * jp;
                *(u32*)&sTh[(kt * 16 + lr) * SP + col] = (u32)ha | ((u32)hb << 16);
                *(u32*)&sTl[(kt * 16 + lr) * SP + col] = (u32)la | ((u32)lb << 16);
            }
            redf[(kt * 16 + lr) * 17 + (w & 3) * 4 + lg] = psum[kt];
        }
    }
    __syncthreads();
    if (tid < 64) {
        float sd = 0.f;
        #pragma unroll
        for (int g2 = 0; g2 < 16; g2++) sd += redf[tid * 17 + g2];
        dpart[((size_t)(b * 64 + ch)) * K + tid] = sd;
    }

    // ---- M: sigmaT(LDS) x reg B-frags -> chunked plain stores ----
    f32x4 macc[8];
    #pragma unroll
    for (int t2 = 0; t2 < 8; t2++) macc[t2] = z4;
    #pragma unroll
    for (int nn2 = 0; nn2 < 2; nn2++) {
        int no = nn2 * 32 + lg * 8;
        bf16x8 Ah[4], Al[4];
        #pragma unroll
        for (int kt2 = 0; kt2 < 4; kt2++) {
            Ah[kt2] = *(bf16x8*)&sTh[(kt2 * 16 + lr) * SP + no];
            Al[kt2] = *(bf16x8*)&sTl[(kt2 * 16 + lr) * SP + no];
        }
        #pragma unroll
        for (int cio = 0; cio < 2; cio++) {
            #pragma unroll
            for (int kt2 = 0; kt2 < 4; kt2++) {
                macc[kt2 * 2 + cio] = __builtin_amdgcn_mfma_f32_16x16x32_bf16(Ah[kt2], mBh[nn2 * 2 + cio], macc[kt2 * 2 + cio], 0, 0, 0);
                macc[kt2 * 2 + cio] = __builtin_amdgcn_mfma_f32_16x16x32_bf16(Al[kt2], mBh[nn2 * 2 + cio], macc[kt2 * 2 + cio], 0, 0, 0);
                macc[kt2 * 2 + cio] = __builtin_amdgcn_mfma_f32_16x16x32_bf16(Ah[kt2], mBl[nn2 * 2 + cio], macc[kt2 * 2 + cio], 0, 0, 0);
            }
        }
    }
    #pragma unroll
    for (int kt2 = 0; kt2 < 4; kt2++)
        #pragma unroll
        for (int cio = 0; cio < 2; cio++)
            #pragma unroll
            for (int jj = 0; jj < 4; jj++) {
                int kk = kt2 * 16 + lg * 4 + jj;
                int c = (w * 2 + cio) * 16 + lr;
                tpart[((size_t)((b * 64 + ch) * K + kk)) * C + c] = macc[kt2 * 2 + cio][jj];
            }
}

// ================= reduce + l2norm -> muT (+ fused pmat, + mu output) =================
// grid (K, B), block 256 (tid = c, and tid = o for pmat)
__global__ __launch_bounds__(256) void k_norm(
        const float* __restrict__ tpart, const float* __restrict__ dpart,
        u16* __restrict__ muth, u16* __restrict__ mutl,
        u16* __restrict__ Pb, const u16* __restrict__ wch, const u16* __restrict__ wcl,
        float* __restrict__ out_mu, float dconst, int s_pm, int last) {
    __shared__ float red[256];
    __shared__ float murow[256];
    __shared__ float dsh;
    int k = blockIdx.x, b = blockIdx.y, tid = threadIdx.x;
    float dv = 0.f;
    if (tid < 64) dv = dpart[((size_t)(b * 64 + tid)) * K + k];
    #pragma unroll
    for (int off = 1; off <= 32; off <<= 1) dv += __shfl_xor(dv, off);
    if (tid == 0) dsh = dv;
    float tt = 0.f;
    #pragma unroll 8
    for (int chn = 0; chn < 64; chn++)
        tt += tpart[((size_t)((b * 64 + chn) * K + k)) * C + tid];
    red[tid] = tt * tt;
    __syncthreads();
    for (int st = 128; st > 0; st >>= 1) {
        if (tid < st) red[tid] += red[tid + st];
        __syncthreads();
    }
    float d = dconst + dsh;
    float inv = 1.f / (1e-6f * d + sqrtf(red[0]));
    float v = tt * inv;
    murow[tid] = v;
    u16 hh = bf_hi(v);
    size_t o = ((size_t)(b * K + k)) * C + tid;
    muth[o] = hh;
    mutl[o] = bf_hi(v - bf_f(hh));
    if (last) out_mu[((size_t)(b * C + tid)) * K + k] = v;
    if (s_pm >= 0) {
        __syncthreads();
        const u16* wh = wch + (size_t)tid * W3C + s_pm * C;
        const u16* wl = wcl + (size_t)tid * W3C + s_pm * C;
        float accp = 0.f;
        #pragma unroll 4
        for (int c8 = 0; c8 < 32; c8++) {
            u16x8 hv = *(const u16x8*)&wh[c8 * 8];
            u16x8 lv = *(const u16x8*)&wl[c8 * 8];
            #pragma unroll
            for (int j = 0; j < 8; j++)
                accp += (bf_f(hv[j]) + bf_f(lv[j])) * murow[c8 * 8 + j];
        }
        Pb[((size_t)((s_pm * B + b) * C + tid)) * K + k] = bf_hi(accp);
    }
}

// ================= final: out = relu(w*(sum_s sig_s P_s^T + b_cat) + x) =================
__global__ __launch_bounds__(256) void k_final(
        const u16* __restrict__ sh_g, const u16* __restrict__ Pb,
        const float* __restrict__ x, const float* __restrict__ b_cat,
        const float* __restrict__ wscal, float* __restrict__ out) {
    __shared__ u16 ssig[64 * 72];
    __shared__ u16 sP[64 * 72];
    __shared__ float tbuf[64 * 68];
    int nt = blockIdx.x, ot = blockIdx.y, b = blockIdx.z;
    int n0 = nt * 64, o0 = ot * 64;
    int tid = threadIdx.x, w = tid >> 6, l = tid & 63, lg = l >> 4, lr = l & 15;
    f32x4 z4 = {0.f, 0.f, 0.f, 0.f};
    f32x4 acc[4] = {z4, z4, z4, z4};
    for (int s = 0; s < 3; s++) {
        __syncthreads();
        for (int t = tid; t < 512; t += 256) {
            int r = t >> 3, kc = (t & 7) * 8;
            *(u16x8*)&ssig[r * 72 + kc] =
                *(const u16x8*)&sh_g[(size_t)s * ((size_t)B * NN * K) + ((size_t)(b * NN + n0 + r)) * K + kc];
            *(u16x8*)&sP[r * 72 + kc] =
                *(const u16x8*)&Pb[((size_t)((s * B + b) * C + o0 + r)) * K + kc];
        }
        __syncthreads();
        #pragma unroll
        for (int kk = 0; kk < 2; kk++) {
            int ko = kk * 32 + lg * 8;
            bf16x8 A = *(bf16x8*)&ssig[(w * 16 + lr) * 72 + ko];
            #pragma unroll
            for (int oi = 0; oi < 4; oi++) {
                bf16x8 Bv = *(bf16x8*)&sP[(oi * 16 + lr) * 72 + ko];
                acc[oi] = __builtin_amdgcn_mfma_f32_16x16x32_bf16(A, Bv, acc[oi], 0, 0, 0);
            }
        }
    }
    __syncthreads();
    #pragma unroll
    for (int oi = 0; oi < 4; oi++)
        #pragma unroll
        for (int jj = 0; jj < 4; jj++)
            tbuf[(oi * 16 + lr) * 68 + (w * 16 + lg * 4 + jj)] = acc[oi][jj];
    __syncthreads();
    float wv = wscal[0];
    for (int t = tid; t < 1024; t += 256) {
        int ol = t >> 4, ck = (t & 15) * 4;
        int o = o0 + ol;
        float bc = b_cat[o];
        float4 u4 = *(float4*)&tbuf[ol * 68 + ck];
        size_t base = ((size_t)(b * C + o)) * NN + n0 + ck;
        float4 xv = *(const float4*)&x[base];
        float4 r;
        r.x = fmaxf((u4.x + bc) * wv + xv.x, 0.f);
        r.y = fmaxf((u4.y + bc) * wv + xv.y, 0.f);
        r.z = fmaxf((u4.z + bc) * wv + xv.z, 0.f);
        r.w = fmaxf((u4.w + bc) * wv + xv.w, 0.f);
        *(float4*)&out[base] = r;
    }
}

extern "C" void kernel_launch(void* const* d_in, const int* in_sizes, int n_in,
                              void* d_out, int out_size, void* d_ws, size_t ws_size,
                              hipStream_t stream) {
    const float* x     = (const float*)d_in[0];
    const float* mu0   = (const float*)d_in[1];
    const float* wsc   = (const float*)d_in[2];
    const float* w_cat = (const float*)d_in[3];
    const float* b_cat = (const float*)d_in[4];
    float* out = (float*)d_out;
    char* wsb = (char*)d_ws;

    const size_t SZ_X2   = (size_t)B * C * NN * 2;     // 8 MB
    const size_t SZ_MUT  = (size_t)B * K * C * 2;      // 128 KB
    const size_t SZ_SIGH = (size_t)3 * B * NN * K * 2; // 6 MB
    const size_t SZ_TP   = (size_t)B * 64 * K * C * 4; // 16 MB (chunked)
    const size_t SZ_DP   = (size_t)B * 64 * K * 4;     // 64 KB
    const size_t SZ_PB   = (size_t)3 * B * C * K * 2;  // 384 KB
    const size_t SZ_WC   = (size_t)C * W3C * 2;        // 384 KB

    size_t off = 0;
    u16*   xch  = (u16*)(wsb + off); off += SZ_X2;
    u16*   xcl  = (u16*)(wsb + off); off += SZ_X2;
    u16*   xth  = (u16*)(wsb + off); off += SZ_X2;
    u16*   xtl  = (u16*)(wsb + off); off += SZ_X2;
    u16*   muth = (u16*)(wsb + off); off += SZ_MUT;
    u16*   mutl = (u16*)(wsb + off); off += SZ_MUT;
    u16*   sigh = (u16*)(wsb + off); off += SZ_SIGH;
    float* tpart= (float*)(wsb + off); off += SZ_TP;
    float* dpart= (float*)(wsb + off); off += SZ_DP;
    u16*   Pb   = (u16*)(wsb + off); off += SZ_PB;
    u16*   wch  = (u16*)(wsb + off); off += SZ_WC;
    u16*   wcl  = (u16*)(wsb + off); off += SZ_WC;
    float* out_mu = out + (size_t)B * C * NN;

    const int EM_LDS = 2 * 64 * CP * 2 + 64 * LGP * 4 + 2 * 64 * SP * 2 + 1152 * 4; // 108,032
    hipFuncSetAttribute((const void*)k_em, hipFuncAttributeMaxDynamicSharedMemorySize, EM_LDS);

    k_prep<<<6496, 256, 0, stream>>>(x, mu0, w_cat, xch, xcl, wch, wcl, muth, mutl, xth, xtl);

    const float dconsts[3] = {1e-6f, 1e-6f + 11.9375f, 1e-6f + 59.4375f};

    for (int i = 0; i < 9; i++) {
        int s = i / 3;
        u16* shs = sigh + (size_t)s * ((size_t)B * NN * K);
        k_em<<<dim3(64, B), 512, EM_LDS, stream>>>(
            xth, xtl, xch, xcl, muth, mutl, tpart, dpart, shs, s, (i % 3 == 2) ? 1 : 0);
        k_norm<<<dim3(K, B), 256, 0, stream>>>(
            tpart, dpart, muth, mutl, Pb, wch, wcl, out_mu,
            dconsts[s], (i % 3 == 2) ? s : -1, (i == 8) ? 1 : 0);
    }
    k_final<<<dim3(64, 4, B), 256, 0, stream>>>(sigh, Pb, x, b_cat, wsc, out);
}